// Round 7
// baseline (605.341 us; speedup 1.0000x reference)
//
#include <hip/hip_runtime.h>
#include <hip/hip_bf16.h>

// ExpertODEEnsemble: E=8, D=64, H=512, B=32768.
// R7 = R5 (64-row tiles, 8-wave blocks, e-loop, register combine) +
//  (1) grid = 512 blocks (exactly 2/CU, co-resident) with a timing-only
//      soft grid barrier between experts -> all blocks on an XCD stream the
//      SAME expert's 1.15 MB weights -> L2-resident -> ~200cyc A-loads that
//      depth-2 prefetch covers. Bounded spin: cannot deadlock; timing-only.
//  (2) wave-contiguous weight layout [w][kc][ol][lane]: each wave streams
//      sequential memory.

typedef unsigned short ushort_t;
typedef unsigned int u32;
typedef unsigned long long u64;
typedef __attribute__((ext_vector_type(8))) short short8;
typedef __attribute__((ext_vector_type(4))) float floatx4;
typedef __attribute__((ext_vector_type(16))) float floatx16;
typedef __attribute__((ext_vector_type(4))) int intx4;

// ws layout (bytes); granule = 16 B = 8 bf16 along k
#define W1A_OFF 0u          // per e: granule ((w*4+kc)*2+ol)*64+lane
#define W2A_OFF 524288u     // per e: granule ((w*32+kc)*2+ol)*64+lane
#define W3A_OFF 4718592u
#define W4A_OFF 8912896u    // per e: granule (o4*32+kc)*64+lane
#define XB_OFF  9437184u    // x row-major bf16 [32768][64]
#define B1E_OFF 13631488u   // b1_eff fp32 [8][512]
#define CTR_OFF 13647872u   // 8 ints: soft grid-barrier counters

static __device__ __forceinline__ u32 pk2bf(float a, float b) {
  union { __hip_bfloat162 h; u32 u; } v;
  v.h = __float22bfloat162_rn(make_float2(a, b));
  return v.u;
}

static __device__ __forceinline__ float pade_tanh(float x) {
  // tanh x = x(945+105x^2+x^4)/(945+420x^2+15x^4); |err|<=1e-4 for |x|<=2
  float x2 = x * x;
  float num = __builtin_fmaf(x2, __builtin_fmaf(x2, 1.0f, 105.0f), 945.0f);
  float den = __builtin_fmaf(x2, __builtin_fmaf(x2, 15.0f, 420.0f), 945.0f);
  return x * num * __builtin_amdgcn_rcpf(den);
}

static __device__ __forceinline__ void ald16(const void* g, void* l) {
  __builtin_amdgcn_global_load_lds((__attribute__((address_space(1))) void*)g,
                                   (__attribute__((address_space(3))) void*)l,
                                   16, 0, 0);
}

static __device__ __forceinline__ floatx16 mfma32(short8 a, short8 b, floatx16 c) {
  return __builtin_amdgcn_mfma_f32_32x32x16_bf16(a, b, c, 0, 0, 0);
}

// ---------------- prep: one 16B dest granule per thread ----------------------
__global__ __launch_bounds__(256) void prep_kernel(
    const float* __restrict__ t, const float* __restrict__ x,
    const float* __restrict__ omega, const float* __restrict__ W1,
    const float* __restrict__ b1, const float* __restrict__ W2,
    const float* __restrict__ W3, const float* __restrict__ W4,
    char* __restrict__ ws) {
  int i = blockIdx.x * 256 + threadIdx.x;
  if (i < 32768) {                       // W1A: e,outr<512,kg<8 (row stride 67)
    int e = i >> 12, rem = i & 4095, outr = rem >> 3, kg = rem & 7;
    int lane = (outr & 31) | ((kg & 1) << 5);
    int w = outr >> 6, ol = (outr >> 5) & 1, kc = kg >> 1;
    int dest = e * 4096 + ((w * 4 + kc) * 2 + ol) * 64 + lane;
    const float* s = W1 + (e * 512 + outr) * 67 + kg * 8;
    ((intx4*)(ws + W1A_OFF))[dest] = (intx4){
        (int)pk2bf(s[0], s[1]), (int)pk2bf(s[2], s[3]),
        (int)pk2bf(s[4], s[5]), (int)pk2bf(s[6], s[7])};
    return;
  }
  i -= 32768;
  if (i < 262144) {                      // W2A: e,outr<512,kg<64
    int e = i >> 15, rem = i & 32767, outr = rem >> 6, kg = rem & 63;
    int lane = (outr & 31) | ((kg & 1) << 5);
    int w = outr >> 6, ol = (outr >> 5) & 1, kc = kg >> 1;
    int dest = e * 32768 + ((w * 32 + kc) * 2 + ol) * 64 + lane;
    const floatx4* s = (const floatx4*)(W2 + ((e << 9) + outr) * 512 + (kg << 3));
    floatx4 lo = s[0], hi = s[1];
    ((intx4*)(ws + W2A_OFF))[dest] = (intx4){
        (int)pk2bf(lo[0], lo[1]), (int)pk2bf(lo[2], lo[3]),
        (int)pk2bf(hi[0], hi[1]), (int)pk2bf(hi[2], hi[3])};
    return;
  }
  i -= 262144;
  if (i < 262144) {                      // W3A
    int e = i >> 15, rem = i & 32767, outr = rem >> 6, kg = rem & 63;
    int lane = (outr & 31) | ((kg & 1) << 5);
    int w = outr >> 6, ol = (outr >> 5) & 1, kc = kg >> 1;
    int dest = e * 32768 + ((w * 32 + kc) * 2 + ol) * 64 + lane;
    const floatx4* s = (const floatx4*)(W3 + ((e << 9) + outr) * 512 + (kg << 3));
    floatx4 lo = s[0], hi = s[1];
    ((intx4*)(ws + W3A_OFF))[dest] = (intx4){
        (int)pk2bf(lo[0], lo[1]), (int)pk2bf(lo[2], lo[3]),
        (int)pk2bf(hi[0], hi[1]), (int)pk2bf(hi[2], hi[3])};
    return;
  }
  i -= 262144;
  if (i < 32768) {                       // W4A: e,outr<64,kg<64
    int e = i >> 12, rem = i & 4095, outr = rem >> 6, kg = rem & 63;
    int lane = (outr & 31) | ((kg & 1) << 5);
    int o4 = outr >> 5, kc = kg >> 1;
    int dest = e * 4096 + (o4 * 32 + kc) * 64 + lane;
    const floatx4* s = (const floatx4*)(W4 + ((e << 6) + outr) * 512 + (kg << 3));
    floatx4 lo = s[0], hi = s[1];
    ((intx4*)(ws + W4A_OFF))[dest] = (intx4){
        (int)pk2bf(lo[0], lo[1]), (int)pk2bf(lo[2], lo[3]),
        (int)pk2bf(hi[0], hi[1]), (int)pk2bf(hi[2], hi[3])};
    return;
  }
  i -= 32768;
  if (i < 262144) {                      // x -> bf16, row-major
    const floatx4* s = (const floatx4*)(x + i * 8);
    floatx4 lo = s[0], hi = s[1];
    ((intx4*)(ws + XB_OFF))[i] = (intx4){
        (int)pk2bf(lo[0], lo[1]), (int)pk2bf(lo[2], lo[3]),
        (int)pk2bf(hi[0], hi[1]), (int)pk2bf(hi[2], hi[3])};
    return;
  }
  i -= 262144;
  if (i < 4096) {                        // b1_eff: fold t/sin/cos cols of W1
    float tv = t[0];
    int e = i >> 9;
    float om = omega[e];
    ((float*)(ws + B1E_OFF))[i] = b1[i] + tv * W1[i * 67 + 64]
        + sinf(om * tv) * W1[i * 67 + 65] + cosf(om * tv) * W1[i * 67 + 66];
    return;
  }
  i -= 4096;
  if (i < 8) ((int*)(ws + CTR_OFF))[i] = 0;   // barrier counters
}

// act LDS (64 rows): granule f(row, koct) = (koct>>1)*132 + (row>>5)*64
//                    + (koct&1)*32 + (row&31); koct 0..63, rows 0..63.
// B-frag (kc,nt): granules kc*132 + nt*64 + lane -> stride-1 1KB, conflict-free.

template <int NKC, bool WRAP>
static __device__ __forceinline__ void mlp_layer(
    const char* __restrict__ bsrc, char* __restrict__ dst,
    int lane, int w, int q1, int r31,
    const short8* __restrict__ Abase, const float* __restrict__ bias) {
  const short8* Ap = Abase + w * (NKC * 128) + lane;   // wave-contiguous stream
  floatx16 acc[2][2];
#pragma unroll
  for (int ol = 0; ol < 2; ++ol) {
    int fe0 = (2 * w + ol) * 32 + 4 * q1;
#pragma unroll
    for (int g = 0; g < 4; ++g) {
      floatx4 bv = *(const floatx4*)(bias + fe0 + 8 * g);
#pragma unroll
      for (int nt = 0; nt < 2; ++nt) {
        acc[ol][nt][4 * g + 0] = bv[0];
        acc[ol][nt][4 * g + 1] = bv[1];
        acc[ol][nt][4 * g + 2] = bv[2];
        acc[ol][nt][4 * g + 3] = bv[3];
      }
    }
  }
  // depth-2 A prefetch (L2-resident ~200cyc), depth-2 B prefetch (LDS)
  short8 a_c[2], a_n[2], b_c[2], b_n[2];
  a_c[0] = Ap[0];   a_c[1] = Ap[64];
  a_n[0] = Ap[128]; a_n[1] = Ap[192];
  b_c[0] = *(const short8*)(bsrc + ((0 * 132 + 0 * 64 + lane) << 4));
  b_c[1] = *(const short8*)(bsrc + ((0 * 132 + 1 * 64 + lane) << 4));
  b_n[0] = *(const short8*)(bsrc + ((1 * 132 + 0 * 64 + lane) << 4));
  b_n[1] = *(const short8*)(bsrc + ((1 * 132 + 1 * 64 + lane) << 4));

#pragma unroll 4
  for (int kc = 0; kc < NKC; ++kc) {
    short8 ac0 = a_c[0], ac1 = a_c[1], bc0 = b_c[0], bc1 = b_c[1];
    a_c[0] = a_n[0]; a_c[1] = a_n[1];
    b_c[0] = b_n[0]; b_c[1] = b_n[1];
    a_n[0] = Ap[(kc + 2) * 128];                 // unguarded: lands in ws
    a_n[1] = Ap[(kc + 2) * 128 + 64];
    const int kp = WRAP ? ((kc + 2) & (NKC - 1)) : (kc + 2);
    b_n[0] = *(const short8*)(bsrc + ((kp * 132 + 0 * 64 + lane) << 4));
    b_n[1] = *(const short8*)(bsrc + ((kp * 132 + 1 * 64 + lane) << 4));
    acc[0][0] = mfma32(ac0, bc0, acc[0][0]);
    acc[0][1] = mfma32(ac0, bc1, acc[0][1]);
    acc[1][0] = mfma32(ac1, bc0, acc[1][0]);
    acc[1][1] = mfma32(ac1, bc1, acc[1][1]);
  }
  __syncthreads();                               // all act reads done
#pragma unroll
  for (int ol = 0; ol < 2; ++ol) {
    int o_abs = 2 * w + ol;
#pragma unroll
    for (int g = 0; g < 4; ++g) {
      int koct = o_abs * 4 + g;
      char* base = dst + ((((koct >> 1) * 132 + (koct & 1) * 32 + r31) << 4) + q1 * 8);
#pragma unroll
      for (int nt = 0; nt < 2; ++nt) {
        float v0 = pade_tanh(acc[ol][nt][4 * g + 0]);
        float v1 = pade_tanh(acc[ol][nt][4 * g + 1]);
        float v2 = pade_tanh(acc[ol][nt][4 * g + 2]);
        float v3 = pade_tanh(acc[ol][nt][4 * g + 3]);
        u32 lo = pk2bf(v0, v1), hi = pk2bf(v2, v3);
        *(u64*)(base + nt * 1024) = ((u64)hi << 32) | lo;
      }
    }
  }
  __syncthreads();                               // act_{n+1} visible
}

__global__ __launch_bounds__(512, 4) void fused_kernel(
    const char* __restrict__ ws, const float* __restrict__ b2,
    const float* __restrict__ b3, const float* __restrict__ b4,
    const float* __restrict__ ew, float* __restrict__ out) {
  __shared__ char smem[80256];           // 71808 act (+pf pad) | 8448 x region
  char* xreg = smem + 71808;
  int* ctr = (int*)(ws + CTR_OFF);
  const int t = threadIdx.x, lane = t & 63, w = t >> 6;
  const int q1 = lane >> 5, r31 = lane & 31;
  const int xcd = blockIdx.x & 7;        // XCD proxy for expert stagger
  const int row0 = blockIdx.x << 6;      // 64-row tile, 512 blocks (2/CU)

  // stage x once (kc 0..3): 1 shot/wave into x region
  const ushort_t* xb = (const ushort_t*)(ws + XB_OFF);
  ald16(xb + (row0 + (w & 1) * 32 + r31) * 64 + ((w >> 1) * 2 + q1) * 8,
        xreg + (((w >> 1) * 132 + (w & 1) * 64) << 4));

  const int o4 = w & 1, nt4 = (w >> 1) & 1, kh = w >> 2;
  const int row_l4 = row0 + nt4 * 32 + r31;
  const int fe0 = o4 * 32 + 4 * q1;
  floatx16 out_acc = {};

  __syncthreads();                       // x staged

  const short8* W1A = (const short8*)(ws + W1A_OFF);
  const short8* W2A = (const short8*)(ws + W2A_OFF);
  const short8* W3A = (const short8*)(ws + W3A_OFF);
  const short8* W4A = (const short8*)(ws + W4A_OFF);
  const float* B1E = (const float*)(ws + B1E_OFF);

  for (int ei = 0; ei < 8; ++ei) {
    const int e = (xcd + ei) & 7;
    const float sc = ew[row_l4 * 8 + e];

    mlp_layer<4, true>(xreg, smem, lane, w, q1, r31, W1A + e * 4096, B1E + e * 512);
    mlp_layer<32, false>(smem, smem, lane, w, q1, r31, W2A + e * 32768, b2 + e * 512);
    mlp_layer<32, false>(smem, smem, lane, w, q1, r31, W3A + e * 32768, b3 + e * 512);

    // L4: K-half kh, feat-half o4, row-half nt4 -> weighted into out_acc
    {
      const short8* Ap = W4A + e * 4096 + (o4 * 32 + kh * 16) * 64 + lane;
      floatx16 acc = {};
      short8 a_c = Ap[0], a_n = Ap[64];
      short8 b_c = *(const short8*)(smem + (((kh * 16) * 132 + nt4 * 64 + lane) << 4));
      short8 b_n = *(const short8*)(smem + (((kh * 16 + 1) * 132 + nt4 * 64 + lane) << 4));
#pragma unroll 4
      for (int kcl = 0; kcl < 16; ++kcl) {
        short8 ac = a_c, bc = b_c;
        a_c = a_n; b_c = b_n;
        a_n = Ap[(kcl + 2) * 64];                // unguarded: in-ws
        b_n = *(const short8*)(smem + (((kh * 16 + kcl + 2) * 132 + nt4 * 64 + lane) << 4));
        acc = mfma32(ac, bc, acc);
      }
      if (kh == 0) {                     // bias added once (kh=0 partner)
        const float* bp = b4 + e * 64 + fe0;
#pragma unroll
        for (int g = 0; g < 4; ++g) {
          floatx4 bv = *(const floatx4*)(bp + 8 * g);
          out_acc[4 * g + 0] += sc * (acc[4 * g + 0] + bv[0]);
          out_acc[4 * g + 1] += sc * (acc[4 * g + 1] + bv[1]);
          out_acc[4 * g + 2] += sc * (acc[4 * g + 2] + bv[2]);
          out_acc[4 * g + 3] += sc * (acc[4 * g + 3] + bv[3]);
        }
      } else {
#pragma unroll
        for (int i = 0; i < 16; ++i) out_acc[i] += sc * acc[i];
      }
    }

    // ---- timing-only soft grid barrier: keep all blocks on the same expert
    // (per-XCD L2 weight residency). Bounded spin -> can never deadlock;
    // correctness does not depend on it (G16-safe).
    if (ei < 7) {
      __syncthreads();                   // also protects act for next L1 epi
      if (t == 0) {
        int* c = ctr + ei;
        __hip_atomic_fetch_add(c, 1, __ATOMIC_RELAXED, __HIP_MEMORY_SCOPE_AGENT);
        for (int s = 0; s < 20000; ++s) {
          if (__hip_atomic_load(c, __ATOMIC_RELAXED, __HIP_MEMORY_SCOPE_AGENT) >= 512)
            break;
          __builtin_amdgcn_s_sleep(2);
        }
      }
      __syncthreads();
    }
  }

  // merge K-half partners (w, w+4) via LDS (act dead), plain stores
  __syncthreads();
  if (w >= 4) {
#pragma unroll
    for (int i = 0; i < 4; ++i) {
      floatx4 p = {out_acc[i * 4 + 0], out_acc[i * 4 + 1],
                   out_acc[i * 4 + 2], out_acc[i * 4 + 3]};
      *(floatx4*)(smem + (w - 4) * 4096 + i * 1024 + lane * 16) = p;
    }
  }
  __syncthreads();
  if (w < 4) {
    float* orow = out + row_l4 * 64 + fe0;
#pragma unroll
    for (int g = 0; g < 4; ++g) {
      floatx4 p = *(const floatx4*)(smem + w * 4096 + g * 1024 + lane * 16);
      floatx4 v = {out_acc[4 * g + 0] + p[0], out_acc[4 * g + 1] + p[1],
                   out_acc[4 * g + 2] + p[2], out_acc[4 * g + 3] + p[3]};
      *(floatx4*)(orow + 8 * g) = v;
    }
  }
}

extern "C" void kernel_launch(void* const* d_in, const int* in_sizes, int n_in,
                              void* d_out, int out_size, void* d_ws, size_t ws_size,
                              hipStream_t stream) {
  const float* t  = (const float*)d_in[0];
  const float* x  = (const float*)d_in[1];
  const float* ew = (const float*)d_in[2];
  const float* om = (const float*)d_in[3];
  const float* W1 = (const float*)d_in[4];
  const float* b1 = (const float*)d_in[5];
  const float* W2 = (const float*)d_in[6];
  const float* b2 = (const float*)d_in[7];
  const float* W3 = (const float*)d_in[8];
  const float* b3 = (const float*)d_in[9];
  const float* W4 = (const float*)d_in[10];
  const float* b4 = (const float*)d_in[11];
  char* ws = (char*)d_ws;
  float* out = (float*)d_out;
  (void)in_sizes; (void)n_in; (void)ws_size; (void)out_size;

  // dest-granule threads: 32768+262144+262144+32768+262144+4096+8 = 856072
  prep_kernel<<<3345, 256, 0, stream>>>(t, x, om, W1, b1, W2, W3, W4, ws);
  fused_kernel<<<512, 512, 0, stream>>>(ws, b2, b3, b4, ew, out);
}

// Round 8
// 586.976 us; speedup vs baseline: 1.0313x; 1.0313x over previous
//
#include <hip/hip_runtime.h>
#include <hip/hip_bf16.h>

// ExpertODEEnsemble: E=8, D=64, H=512, B=32768.
// R8 = R5 shell (64-row tiles, 8-wave blocks, e-loop, register combine, no
// atomics) + instruction-diet K-loop:
//   - A loads: wave-uniform SGPR base (scalar += 2048/iter) + lane*16 voffset
//     (+1024 imm) -> zero per-iter VALU address math.
//   - B ds_reads: fixed vaddr + compile-time immediate offsets (kc*2112).
//   - full unroll + sched_group_barrier 1:1 MFMA<->load interleave.

typedef unsigned short ushort_t;
typedef unsigned int u32;
typedef unsigned long long u64;
typedef __attribute__((ext_vector_type(8))) short short8;
typedef __attribute__((ext_vector_type(4))) float floatx4;
typedef __attribute__((ext_vector_type(16))) float floatx16;
typedef __attribute__((ext_vector_type(4))) int intx4;

#if __has_builtin(__builtin_amdgcn_sched_group_barrier)
#define SGB(m, s, i) __builtin_amdgcn_sched_group_barrier(m, s, i)
#else
#define SGB(m, s, i)
#endif

// ws layout (bytes); granule = 16 B = 8 bf16 along k
#define W1A_OFF 0u          // per e: byte (w*4 +kc)*2048 + ol*1024 + lane*16
#define W2A_OFF 524288u     // per e: byte (w*32+kc)*2048 + ol*1024 + lane*16
#define W3A_OFF 4718592u
#define W4A_OFF 8912896u    // per e: byte o4*32768 + kc*1024 + lane*16
#define XB_OFF  9437184u    // x row-major bf16 [32768][64]
#define B1E_OFF 13631488u   // b1_eff fp32 [8][512]

static __device__ __forceinline__ u32 pk2bf(float a, float b) {
  union { __hip_bfloat162 h; u32 u; } v;
  v.h = __float22bfloat162_rn(make_float2(a, b));
  return v.u;
}

static __device__ __forceinline__ float pade_tanh(float x) {
  // tanh x = x(945+105x^2+x^4)/(945+420x^2+15x^4); |err|<=1e-4 for |x|<=2
  float x2 = x * x;
  float num = __builtin_fmaf(x2, __builtin_fmaf(x2, 1.0f, 105.0f), 945.0f);
  float den = __builtin_fmaf(x2, __builtin_fmaf(x2, 15.0f, 420.0f), 945.0f);
  return x * num * __builtin_amdgcn_rcpf(den);
}

static __device__ __forceinline__ void ald16(const void* g, void* l) {
  __builtin_amdgcn_global_load_lds((__attribute__((address_space(1))) void*)g,
                                   (__attribute__((address_space(3))) void*)l,
                                   16, 0, 0);
}

static __device__ __forceinline__ floatx16 mfma32(short8 a, short8 b, floatx16 c) {
  return __builtin_amdgcn_mfma_f32_32x32x16_bf16(a, b, c, 0, 0, 0);
}

// ---------------- prep: one 16B dest granule per thread ----------------------
__global__ __launch_bounds__(256) void prep_kernel(
    const float* __restrict__ t, const float* __restrict__ x,
    const float* __restrict__ omega, const float* __restrict__ W1,
    const float* __restrict__ b1, const float* __restrict__ W2,
    const float* __restrict__ W3, const float* __restrict__ W4,
    char* __restrict__ ws) {
  int i = blockIdx.x * 256 + threadIdx.x;
  if (i < 32768) {                       // W1A: e,outr<512,kg<8 (row stride 67)
    int e = i >> 12, rem = i & 4095, outr = rem >> 3, kg = rem & 7;
    int lane = (outr & 31) | ((kg & 1) << 5);
    int w = outr >> 6, ol = (outr >> 5) & 1, kc = kg >> 1;
    int dest = e * 4096 + ((w * 4 + kc) * 2 + ol) * 64 + lane;
    const float* s = W1 + (e * 512 + outr) * 67 + kg * 8;
    ((intx4*)(ws + W1A_OFF))[dest] = (intx4){
        (int)pk2bf(s[0], s[1]), (int)pk2bf(s[2], s[3]),
        (int)pk2bf(s[4], s[5]), (int)pk2bf(s[6], s[7])};
    return;
  }
  i -= 32768;
  if (i < 262144) {                      // W2A: e,outr<512,kg<64
    int e = i >> 15, rem = i & 32767, outr = rem >> 6, kg = rem & 63;
    int lane = (outr & 31) | ((kg & 1) << 5);
    int w = outr >> 6, ol = (outr >> 5) & 1, kc = kg >> 1;
    int dest = e * 32768 + ((w * 32 + kc) * 2 + ol) * 64 + lane;
    const floatx4* s = (const floatx4*)(W2 + ((e << 9) + outr) * 512 + (kg << 3));
    floatx4 lo = s[0], hi = s[1];
    ((intx4*)(ws + W2A_OFF))[dest] = (intx4){
        (int)pk2bf(lo[0], lo[1]), (int)pk2bf(lo[2], lo[3]),
        (int)pk2bf(hi[0], hi[1]), (int)pk2bf(hi[2], hi[3])};
    return;
  }
  i -= 262144;
  if (i < 262144) {                      // W3A
    int e = i >> 15, rem = i & 32767, outr = rem >> 6, kg = rem & 63;
    int lane = (outr & 31) | ((kg & 1) << 5);
    int w = outr >> 6, ol = (outr >> 5) & 1, kc = kg >> 1;
    int dest = e * 32768 + ((w * 32 + kc) * 2 + ol) * 64 + lane;
    const floatx4* s = (const floatx4*)(W3 + ((e << 9) + outr) * 512 + (kg << 3));
    floatx4 lo = s[0], hi = s[1];
    ((intx4*)(ws + W3A_OFF))[dest] = (intx4){
        (int)pk2bf(lo[0], lo[1]), (int)pk2bf(lo[2], lo[3]),
        (int)pk2bf(hi[0], hi[1]), (int)pk2bf(hi[2], hi[3])};
    return;
  }
  i -= 262144;
  if (i < 32768) {                       // W4A: e,outr<64,kg<64
    int e = i >> 12, rem = i & 4095, outr = rem >> 6, kg = rem & 63;
    int lane = (outr & 31) | ((kg & 1) << 5);
    int o4 = outr >> 5, kc = kg >> 1;
    int dest = e * 4096 + (o4 * 32 + kc) * 64 + lane;
    const floatx4* s = (const floatx4*)(W4 + ((e << 6) + outr) * 512 + (kg << 3));
    floatx4 lo = s[0], hi = s[1];
    ((intx4*)(ws + W4A_OFF))[dest] = (intx4){
        (int)pk2bf(lo[0], lo[1]), (int)pk2bf(lo[2], lo[3]),
        (int)pk2bf(hi[0], hi[1]), (int)pk2bf(hi[2], hi[3])};
    return;
  }
  i -= 32768;
  if (i < 262144) {                      // x -> bf16, row-major
    const floatx4* s = (const floatx4*)(x + i * 8);
    floatx4 lo = s[0], hi = s[1];
    ((intx4*)(ws + XB_OFF))[i] = (intx4){
        (int)pk2bf(lo[0], lo[1]), (int)pk2bf(lo[2], lo[3]),
        (int)pk2bf(hi[0], hi[1]), (int)pk2bf(hi[2], hi[3])};
    return;
  }
  i -= 262144;
  if (i < 4096) {                        // b1_eff: fold t/sin/cos cols of W1
    float tv = t[0];
    int e = i >> 9;
    float om = omega[e];
    ((float*)(ws + B1E_OFF))[i] = b1[i] + tv * W1[i * 67 + 64]
        + sinf(om * tv) * W1[i * 67 + 65] + cosf(om * tv) * W1[i * 67 + 66];
  }
}

// act LDS (64 rows): granule f(row, koct) = (koct>>1)*132 + (row>>5)*64
//                    + (koct&1)*32 + (row&31); byte = kc*2112 + nt*1024 +
//                    (q1*32+r31)*16.  B-read (kc,nt): stride-1 1KB, no conflict.

template <int NKC>
static __device__ __forceinline__ void mlp_layer(
    const char* __restrict__ bsrc, char* __restrict__ dst,
    int lane, int w, int q1, int r31,
    const char* __restrict__ Abase,    // ws offset for this expert's layer
    const float* __restrict__ bias) {
  const int voff = lane * 16;                    // fixed VGPR
  const char* sp = Abase + w * (NKC * 2048);     // wave-uniform -> SGPRs
  const char* bl0 = bsrc + voff;                 // LDS vaddr, nt=0
  const char* bl1 = bl0 + 1024;                  // nt=1

  floatx16 acc[2][2];
#pragma unroll
  for (int ol = 0; ol < 2; ++ol) {
    int fe0 = (2 * w + ol) * 32 + 4 * q1;
#pragma unroll
    for (int g = 0; g < 4; ++g) {
      floatx4 bv = *(const floatx4*)(bias + fe0 + 8 * g);
#pragma unroll
      for (int nt = 0; nt < 2; ++nt) {
        acc[ol][nt][4 * g + 0] = bv[0];
        acc[ol][nt][4 * g + 1] = bv[1];
        acc[ol][nt][4 * g + 2] = bv[2];
        acc[ol][nt][4 * g + 3] = bv[3];
      }
    }
  }
  short8 a_c0 = *(const short8*)(sp + voff);
  short8 a_c1 = *(const short8*)(sp + voff + 1024);
  short8 a_n0 = *(const short8*)(sp + voff + 2048);
  short8 a_n1 = *(const short8*)(sp + voff + 3072);
  sp += 4096;
  short8 b_c0 = *(const short8*)(bl0);
  short8 b_c1 = *(const short8*)(bl1);
  short8 b_n0 = *(const short8*)(bl0 + 2112);
  short8 b_n1 = *(const short8*)(bl1 + 2112);

#pragma unroll
  for (int kc = 0; kc < NKC; ++kc) {
    short8 ac0 = a_c0, ac1 = a_c1, bc0 = b_c0, bc1 = b_c1;
    a_c0 = a_n0; a_c1 = a_n1; b_c0 = b_n0; b_c1 = b_n1;
    a_n0 = *(const short8*)(sp + voff);          // kc+2 slab (overrun: in-ws)
    a_n1 = *(const short8*)(sp + voff + 1024);
    sp += 2048;                                  // uniform -> s_add
    const int kp = (kc + 2) & (NKC - 1);         // wrap: imm stays <64K, in-LDS
    b_n0 = *(const short8*)(bl0 + kp * 2112);
    b_n1 = *(const short8*)(bl1 + kp * 2112);
    acc[0][0] = mfma32(ac0, bc0, acc[0][0]);
    acc[0][1] = mfma32(ac0, bc1, acc[0][1]);
    acc[1][0] = mfma32(ac1, bc0, acc[1][0]);
    acc[1][1] = mfma32(ac1, bc1, acc[1][1]);
    SGB(0x100, 1, 0);  // 1 DS read
    SGB(0x008, 1, 0);  // 1 MFMA
    SGB(0x020, 1, 0);  // 1 VMEM read
    SGB(0x008, 1, 0);  // 1 MFMA
    SGB(0x100, 1, 0);
    SGB(0x008, 1, 0);
    SGB(0x020, 1, 0);
    SGB(0x008, 1, 0);
  }
  __syncthreads();                               // all act reads done
#pragma unroll
  for (int ol = 0; ol < 2; ++ol) {
    int o_abs = 2 * w + ol;
#pragma unroll
    for (int g = 0; g < 4; ++g) {
      int koct = o_abs * 4 + g;
      char* base = dst + ((((koct >> 1) * 132 + (koct & 1) * 32 + r31) << 4) + q1 * 8);
#pragma unroll
      for (int nt = 0; nt < 2; ++nt) {
        float v0 = pade_tanh(acc[ol][nt][4 * g + 0]);
        float v1 = pade_tanh(acc[ol][nt][4 * g + 1]);
        float v2 = pade_tanh(acc[ol][nt][4 * g + 2]);
        float v3 = pade_tanh(acc[ol][nt][4 * g + 3]);
        u32 lo = pk2bf(v0, v1), hi = pk2bf(v2, v3);
        *(u64*)(base + nt * 1024) = ((u64)hi << 32) | lo;
      }
    }
  }
  __syncthreads();                               // act_{n+1} visible
}

__global__ __launch_bounds__(512, 4) void fused_kernel(
    const char* __restrict__ ws, const float* __restrict__ b2,
    const float* __restrict__ b3, const float* __restrict__ b4,
    const float* __restrict__ ew, float* __restrict__ out) {
  __shared__ char smem[76032];           // 67584 act | 8448 x (wrap, no pad)
  char* xreg = smem + 67584;
  const int t = threadIdx.x, lane = t & 63, w = t >> 6;
  const int q1 = lane >> 5, r31 = lane & 31;
  const int xcd = blockIdx.x & 7;        // expert-order stagger
  const int row0 = blockIdx.x << 6;      // 64-row tile, 512 blocks (2/CU)

  // stage x once (kc 0..3): 1 shot/wave into x region
  const ushort_t* xb = (const ushort_t*)(ws + XB_OFF);
  ald16(xb + (row0 + (w & 1) * 32 + r31) * 64 + ((w >> 1) * 2 + q1) * 8,
        xreg + (((w >> 1) * 132 + (w & 1) * 64) << 4));

  const int o4 = w & 1, nt4 = (w >> 1) & 1, kh = w >> 2;
  const int row_l4 = row0 + nt4 * 32 + r31;
  const int fe0 = o4 * 32 + 4 * q1;
  const int voff = lane * 16;
  floatx16 out_acc = {};

  __syncthreads();                       // x staged

  for (int ei = 0; ei < 8; ++ei) {
    const int e = (xcd + ei) & 7;
    const float sc = ew[row_l4 * 8 + e];

    mlp_layer<4>(xreg, smem, lane, w, q1, r31,
                 ws + W1A_OFF + e * 65536, (const float*)(ws + B1E_OFF) + e * 512);
    mlp_layer<32>(smem, smem, lane, w, q1, r31,
                  ws + W2A_OFF + e * 524288, b2 + e * 512);
    mlp_layer<32>(smem, smem, lane, w, q1, r31,
                  ws + W3A_OFF + e * 524288, b3 + e * 512);

    // L4: K-half kh, feat-half o4, row-half nt4 -> weighted into out_acc
    {
      const char* sp = ws + W4A_OFF + e * 65536 + o4 * 32768 + kh * 16384;
      const char* bl = smem + nt4 * 1024 + voff;
      floatx16 acc = {};
      short8 a_c = *(const short8*)(sp + voff);
      short8 a_n = *(const short8*)(sp + voff + 1024);
      sp += 2048;
      short8 b_c = *(const short8*)(bl + ((kh * 16) & 31) * 2112);
      short8 b_n = *(const short8*)(bl + ((kh * 16 + 1) & 31) * 2112);
#pragma unroll
      for (int kcl = 0; kcl < 16; ++kcl) {
        short8 ac = a_c, bc = b_c;
        a_c = a_n; b_c = b_n;
        a_n = *(const short8*)(sp + voff);        // overrun: in-ws
        sp += 1024;
        b_n = *(const short8*)(bl + ((kh * 16 + kcl + 2) & 31) * 2112);
        acc = mfma32(ac, bc, acc);
        SGB(0x100, 1, 0);
        SGB(0x008, 1, 0);
        SGB(0x020, 1, 0);
      }
      if (kh == 0) {                     // bias added once (kh=0 partner)
        const float* bp = b4 + e * 64 + fe0;
#pragma unroll
        for (int g = 0; g < 4; ++g) {
          floatx4 bv = *(const floatx4*)(bp + 8 * g);
          out_acc[4 * g + 0] += sc * (acc[4 * g + 0] + bv[0]);
          out_acc[4 * g + 1] += sc * (acc[4 * g + 1] + bv[1]);
          out_acc[4 * g + 2] += sc * (acc[4 * g + 2] + bv[2]);
          out_acc[4 * g + 3] += sc * (acc[4 * g + 3] + bv[3]);
        }
      } else {
#pragma unroll
        for (int i = 0; i < 16; ++i) out_acc[i] += sc * acc[i];
      }
    }
    // next expert's L1 kc-loop reads xreg only; its first barrier protects
    // the act region before the L1 epilogue overwrites it.
  }

  // merge K-half partners (w, w+4) via LDS (act dead), plain stores
  __syncthreads();
  if (w >= 4) {
#pragma unroll
    for (int i = 0; i < 4; ++i) {
      floatx4 p = {out_acc[i * 4 + 0], out_acc[i * 4 + 1],
                   out_acc[i * 4 + 2], out_acc[i * 4 + 3]};
      *(floatx4*)(smem + (w - 4) * 4096 + i * 1024 + lane * 16) = p;
    }
  }
  __syncthreads();
  if (w < 4) {
    float* orow = out + row_l4 * 64 + fe0;
#pragma unroll
    for (int g = 0; g < 4; ++g) {
      floatx4 p = *(const floatx4*)(smem + w * 4096 + g * 1024 + lane * 16);
      floatx4 v = {out_acc[4 * g + 0] + p[0], out_acc[4 * g + 1] + p[1],
                   out_acc[4 * g + 2] + p[2], out_acc[4 * g + 3] + p[3]};
      *(floatx4*)(orow + 8 * g) = v;
    }
  }
}

extern "C" void kernel_launch(void* const* d_in, const int* in_sizes, int n_in,
                              void* d_out, int out_size, void* d_ws, size_t ws_size,
                              hipStream_t stream) {
  const float* t  = (const float*)d_in[0];
  const float* x  = (const float*)d_in[1];
  const float* ew = (const float*)d_in[2];
  const float* om = (const float*)d_in[3];
  const float* W1 = (const float*)d_in[4];
  const float* b1 = (const float*)d_in[5];
  const float* W2 = (const float*)d_in[6];
  const float* b2 = (const float*)d_in[7];
  const float* W3 = (const float*)d_in[8];
  const float* b3 = (const float*)d_in[9];
  const float* W4 = (const float*)d_in[10];
  const float* b4 = (const float*)d_in[11];
  char* ws = (char*)d_ws;
  float* out = (float*)d_out;
  (void)in_sizes; (void)n_in; (void)ws_size; (void)out_size;

  // dest-granule threads: 32768+262144+262144+32768+262144+4096 = 856064
  prep_kernel<<<3344, 256, 0, stream>>>(t, x, om, W1, b1, W2, W3, W4, ws);
  fused_kernel<<<512, 512, 0, stream>>>(ws, b2, b3, b4, ew, out);
}

// Round 9
// 450.108 us; speedup vs baseline: 1.3449x; 1.3041x over previous
//
#include <hip/hip_runtime.h>
#include <hip/hip_bf16.h>

// ExpertODEEnsemble: E=8, D=64, H=512, B=32768.
// R9: 4-wave blocks (256 thr), 64-row tiles, wave tile M=128 x N=64:
// per kc = 4 A-loads + 2 B ds_reads + 8 MFMA  -> LDS traffic /4 vs R5.
// 2 blocks/CU, e-loop with register combine, L4 = 4 tiles for 4 waves
// (full K per wave, no partner merge). Depth-1 prefetch, no SGB, no full
// unroll (R8 spill lesson). __launch_bounds__(256,2) -> 256 VGPR cap.

typedef unsigned short ushort_t;
typedef unsigned int u32;
typedef unsigned long long u64;
typedef __attribute__((ext_vector_type(8))) short short8;
typedef __attribute__((ext_vector_type(4))) float floatx4;
typedef __attribute__((ext_vector_type(16))) float floatx16;
typedef __attribute__((ext_vector_type(4))) int intx4;

// ws layout (bytes); granule = 16 B = 8 bf16 along k
#define W1A_OFF 0u          // per e: byte w*16384 + kc*4096 + ol*1024 + lane*16
#define W2A_OFF 524288u     // per e: byte w*131072 + kc*4096 + ol*1024 + lane*16
#define W3A_OFF 4718592u
#define W4A_OFF 8912896u    // per e: byte o4*32768 + kc*1024 + lane*16
#define XB_OFF  9437184u    // x row-major bf16 [32768][64]
#define B1E_OFF 13631488u   // b1_eff fp32 [8][512]

static __device__ __forceinline__ u32 pk2bf(float a, float b) {
  union { __hip_bfloat162 h; u32 u; } v;
  v.h = __float22bfloat162_rn(make_float2(a, b));
  return v.u;
}

static __device__ __forceinline__ float pade_tanh(float x) {
  // tanh x = x(945+105x^2+x^4)/(945+420x^2+15x^4); |err|<=1e-4 for |x|<=2
  float x2 = x * x;
  float num = __builtin_fmaf(x2, __builtin_fmaf(x2, 1.0f, 105.0f), 945.0f);
  float den = __builtin_fmaf(x2, __builtin_fmaf(x2, 15.0f, 420.0f), 945.0f);
  return x * num * __builtin_amdgcn_rcpf(den);
}

static __device__ __forceinline__ void ald16(const void* g, void* l) {
  __builtin_amdgcn_global_load_lds((__attribute__((address_space(1))) void*)g,
                                   (__attribute__((address_space(3))) void*)l,
                                   16, 0, 0);
}

static __device__ __forceinline__ floatx16 mfma32(short8 a, short8 b, floatx16 c) {
  return __builtin_amdgcn_mfma_f32_32x32x16_bf16(a, b, c, 0, 0, 0);
}

// ---------------- prep: one 16B dest granule per thread ----------------------
__global__ __launch_bounds__(256) void prep_kernel(
    const float* __restrict__ t, const float* __restrict__ x,
    const float* __restrict__ omega, const float* __restrict__ W1,
    const float* __restrict__ b1, const float* __restrict__ W2,
    const float* __restrict__ W3, const float* __restrict__ W4,
    char* __restrict__ ws) {
  int i = blockIdx.x * 256 + threadIdx.x;
  if (i < 32768) {                       // W1A: e,outr<512,kg<8 (row stride 67)
    int e = i >> 12, rem = i & 4095, outr = rem >> 3, kg = rem & 7;
    int lane = (outr & 31) | ((kg & 1) << 5);
    int w = outr >> 7, ol = (outr >> 5) & 3, kc = kg >> 1;
    int dest = e * 4096 + ((w * 4 + kc) * 4 + ol) * 64 + lane;
    const float* s = W1 + (e * 512 + outr) * 67 + kg * 8;
    ((intx4*)(ws + W1A_OFF))[dest] = (intx4){
        (int)pk2bf(s[0], s[1]), (int)pk2bf(s[2], s[3]),
        (int)pk2bf(s[4], s[5]), (int)pk2bf(s[6], s[7])};
    return;
  }
  i -= 32768;
  if (i < 262144) {                      // W2A: e,outr<512,kg<64
    int e = i >> 15, rem = i & 32767, outr = rem >> 6, kg = rem & 63;
    int lane = (outr & 31) | ((kg & 1) << 5);
    int w = outr >> 7, ol = (outr >> 5) & 3, kc = kg >> 1;
    int dest = e * 32768 + ((w * 32 + kc) * 4 + ol) * 64 + lane;
    const floatx4* s = (const floatx4*)(W2 + ((e << 9) + outr) * 512 + (kg << 3));
    floatx4 lo = s[0], hi = s[1];
    ((intx4*)(ws + W2A_OFF))[dest] = (intx4){
        (int)pk2bf(lo[0], lo[1]), (int)pk2bf(lo[2], lo[3]),
        (int)pk2bf(hi[0], hi[1]), (int)pk2bf(hi[2], hi[3])};
    return;
  }
  i -= 262144;
  if (i < 262144) {                      // W3A
    int e = i >> 15, rem = i & 32767, outr = rem >> 6, kg = rem & 63;
    int lane = (outr & 31) | ((kg & 1) << 5);
    int w = outr >> 7, ol = (outr >> 5) & 3, kc = kg >> 1;
    int dest = e * 32768 + ((w * 32 + kc) * 4 + ol) * 64 + lane;
    const floatx4* s = (const floatx4*)(W3 + ((e << 9) + outr) * 512 + (kg << 3));
    floatx4 lo = s[0], hi = s[1];
    ((intx4*)(ws + W3A_OFF))[dest] = (intx4){
        (int)pk2bf(lo[0], lo[1]), (int)pk2bf(lo[2], lo[3]),
        (int)pk2bf(hi[0], hi[1]), (int)pk2bf(hi[2], hi[3])};
    return;
  }
  i -= 262144;
  if (i < 32768) {                       // W4A: e,outr<64,kg<64
    int e = i >> 12, rem = i & 4095, outr = rem >> 6, kg = rem & 63;
    int lane = (outr & 31) | ((kg & 1) << 5);
    int o4 = outr >> 5, kc = kg >> 1;
    int dest = e * 4096 + (o4 * 32 + kc) * 64 + lane;
    const floatx4* s = (const floatx4*)(W4 + ((e << 6) + outr) * 512 + (kg << 3));
    floatx4 lo = s[0], hi = s[1];
    ((intx4*)(ws + W4A_OFF))[dest] = (intx4){
        (int)pk2bf(lo[0], lo[1]), (int)pk2bf(lo[2], lo[3]),
        (int)pk2bf(hi[0], hi[1]), (int)pk2bf(hi[2], hi[3])};
    return;
  }
  i -= 32768;
  if (i < 262144) {                      // x -> bf16, row-major
    const floatx4* s = (const floatx4*)(x + i * 8);
    floatx4 lo = s[0], hi = s[1];
    ((intx4*)(ws + XB_OFF))[i] = (intx4){
        (int)pk2bf(lo[0], lo[1]), (int)pk2bf(lo[2], lo[3]),
        (int)pk2bf(hi[0], hi[1]), (int)pk2bf(hi[2], hi[3])};
    return;
  }
  i -= 262144;
  if (i < 4096) {                        // b1_eff: fold t/sin/cos cols of W1
    float tv = t[0];
    int e = i >> 9;
    float om = omega[e];
    ((float*)(ws + B1E_OFF))[i] = b1[i] + tv * W1[i * 67 + 64]
        + sinf(om * tv) * W1[i * 67 + 65] + cosf(om * tv) * W1[i * 67 + 66];
  }
}

// act LDS (64 rows): granule f(row, koct) = (koct>>1)*132 + (row>>5)*64
//                    + (koct&1)*32 + (row&31);  kc-slab stride 2112 B.
// B-read (kc, nt): byte kc*2112 + nt*1024 + lane*16 -> stride-1, conflict-free.

template <int NKC, bool WRAP>
static __device__ __forceinline__ void mlp_layer(
    const char* __restrict__ bsrc, char* __restrict__ dst,
    int lane, int w, int q1, int r31,
    const char* __restrict__ Abase, const float* __restrict__ bias) {
  const int voff = lane * 16;
  const char* sp = Abase + w * (NKC * 4096) + voff;
  const char* bp = bsrc + voff;

  floatx16 acc[4][2];
#pragma unroll
  for (int ol = 0; ol < 4; ++ol) {
    int fe0 = (4 * w + ol) * 32 + 4 * q1;
#pragma unroll
    for (int g = 0; g < 4; ++g) {
      floatx4 bv = *(const floatx4*)(bias + fe0 + 8 * g);
#pragma unroll
      for (int nt = 0; nt < 2; ++nt) {
        acc[ol][nt][4 * g + 0] = bv[0];
        acc[ol][nt][4 * g + 1] = bv[1];
        acc[ol][nt][4 * g + 2] = bv[2];
        acc[ol][nt][4 * g + 3] = bv[3];
      }
    }
  }
  short8 a0 = *(const short8*)(sp);
  short8 a1 = *(const short8*)(sp + 1024);
  short8 a2 = *(const short8*)(sp + 2048);
  short8 a3 = *(const short8*)(sp + 3072);
  sp += 4096;
  short8 b0 = *(const short8*)(bp);
  short8 b1 = *(const short8*)(bp + 1024);

#pragma unroll 4
  for (int kc = 0; kc < NKC; ++kc) {
    // depth-1 prefetch of kc+1 (A overrun lands in ws; B wraps or overruns
    // into the x region -- loaded-but-never-consumed on the last iter)
    short8 an0 = *(const short8*)(sp);
    short8 an1 = *(const short8*)(sp + 1024);
    short8 an2 = *(const short8*)(sp + 2048);
    short8 an3 = *(const short8*)(sp + 3072);
    const char* bnext = WRAP ? (bsrc + voff + (((kc + 1) & (NKC - 1)) * 2112))
                             : (bp + 2112);
    short8 bn0 = *(const short8*)(bnext);
    short8 bn1 = *(const short8*)(bnext + 1024);
    acc[0][0] = mfma32(a0, b0, acc[0][0]);
    acc[1][0] = mfma32(a1, b0, acc[1][0]);
    acc[2][0] = mfma32(a2, b0, acc[2][0]);
    acc[3][0] = mfma32(a3, b0, acc[3][0]);
    acc[0][1] = mfma32(a0, b1, acc[0][1]);
    acc[1][1] = mfma32(a1, b1, acc[1][1]);
    acc[2][1] = mfma32(a2, b1, acc[2][1]);
    acc[3][1] = mfma32(a3, b1, acc[3][1]);
    a0 = an0; a1 = an1; a2 = an2; a3 = an3;
    b0 = bn0; b1 = bn1;
    sp += 4096;
    bp = bnext;
  }
  __syncthreads();                               // all act reads done
#pragma unroll
  for (int ol = 0; ol < 4; ++ol) {
    int o_abs = 4 * w + ol;
#pragma unroll
    for (int g = 0; g < 4; ++g) {
      int koct = o_abs * 4 + g;
      char* base = dst + ((((koct >> 1) * 132 + (koct & 1) * 32 + r31) << 4) + q1 * 8);
#pragma unroll
      for (int nt = 0; nt < 2; ++nt) {
        float v0 = pade_tanh(acc[ol][nt][4 * g + 0]);
        float v1 = pade_tanh(acc[ol][nt][4 * g + 1]);
        float v2 = pade_tanh(acc[ol][nt][4 * g + 2]);
        float v3 = pade_tanh(acc[ol][nt][4 * g + 3]);
        u32 lo = pk2bf(v0, v1), hi = pk2bf(v2, v3);
        *(u64*)(base + nt * 1024) = ((u64)hi << 32) | lo;
      }
    }
  }
  __syncthreads();                               // act_{n+1} visible
}

__global__ __launch_bounds__(256, 2) void fused_kernel(
    const char* __restrict__ ws, const float* __restrict__ b2,
    const float* __restrict__ b3, const float* __restrict__ b4,
    const float* __restrict__ ew, float* __restrict__ out) {
  __shared__ char smem[76032];           // 67584 act | 8448 x region
  char* xreg = smem + 67584;
  const int t = threadIdx.x, lane = t & 63, w = t >> 6;   // 4 waves
  const int q1 = lane >> 5, r31 = lane & 31;
  const int xcd = blockIdx.x & 7;        // expert-order stagger
  const int row0 = blockIdx.x << 6;      // 64-row tile, 512 blocks (2/CU)
  const int voff = lane * 16;

  // stage x once: wave w -> kc slab w, halves h=0,1
  const ushort_t* xb = (const ushort_t*)(ws + XB_OFF);
  ald16(xb + (row0 + r31) * 64 + w * 16 + q1 * 8, xreg + (w * 132) * 16);
  ald16(xb + (row0 + 32 + r31) * 64 + w * 16 + q1 * 8, xreg + (w * 132 + 64) * 16);

  // L4 assignment: o4 = w&1 (feat half), nt4 = w>>1 (row half), full K
  const int o4 = w & 1, nt4 = w >> 1;
  const int row_l4 = row0 + nt4 * 32 + r31;
  const int fe0 = o4 * 32 + 4 * q1;
  floatx16 out_acc = {};

  __syncthreads();                       // x staged

  for (int ei = 0; ei < 8; ++ei) {
    const int e = (xcd + ei) & 7;
    const float sc = ew[row_l4 * 8 + e];

    mlp_layer<4, true>(xreg, smem, lane, w, q1, r31,
                       ws + W1A_OFF + e * 65536,
                       (const float*)(ws + B1E_OFF) + e * 512);
    mlp_layer<32, false>(smem, smem, lane, w, q1, r31,
                         ws + W2A_OFF + e * 524288, b2 + e * 512);
    mlp_layer<32, false>(smem, smem, lane, w, q1, r31,
                         ws + W3A_OFF + e * 524288, b3 + e * 512);

    // L4: full K=512 per wave, 1 A + 1 B + 1 MFMA per kc
    {
      const char* sp = ws + W4A_OFF + e * 65536 + o4 * 32768 + voff;
      const char* bp = smem + nt4 * 1024 + voff;
      floatx16 acc = {};
      short8 a = *(const short8*)(sp);
      short8 b = *(const short8*)(bp);
      sp += 1024;
#pragma unroll 4
      for (int kc = 0; kc < 32; ++kc) {
        short8 an = *(const short8*)(sp);        // overrun: in-ws
        short8 bn = *(const short8*)(bp + 2112); // overrun: xreg, unused
        acc = mfma32(a, b, acc);
        a = an; b = bn;
        sp += 1024;
        bp += 2112;
      }
      const float* bpb = b4 + e * 64 + fe0;
#pragma unroll
      for (int g = 0; g < 4; ++g) {
        floatx4 bv = *(const floatx4*)(bpb + 8 * g);
        out_acc[4 * g + 0] += sc * (acc[4 * g + 0] + bv[0]);
        out_acc[4 * g + 1] += sc * (acc[4 * g + 1] + bv[1]);
        out_acc[4 * g + 2] += sc * (acc[4 * g + 2] + bv[2]);
        out_acc[4 * g + 3] += sc * (acc[4 * g + 3] + bv[3]);
      }
    }
    // next expert's L1 reads only xreg; its post-kc-loop barrier orders these
    // L4 act reads before the L1 epilogue overwrites the act region.
  }

  // direct store (full-K waves: no partner merge)
  float* orow = out + row_l4 * 64 + fe0;
#pragma unroll
  for (int g = 0; g < 4; ++g) {
    floatx4 v = {out_acc[4 * g + 0], out_acc[4 * g + 1],
                 out_acc[4 * g + 2], out_acc[4 * g + 3]};
    *(floatx4*)(orow + 8 * g) = v;
  }
}

extern "C" void kernel_launch(void* const* d_in, const int* in_sizes, int n_in,
                              void* d_out, int out_size, void* d_ws, size_t ws_size,
                              hipStream_t stream) {
  const float* t  = (const float*)d_in[0];
  const float* x  = (const float*)d_in[1];
  const float* ew = (const float*)d_in[2];
  const float* om = (const float*)d_in[3];
  const float* W1 = (const float*)d_in[4];
  const float* b1 = (const float*)d_in[5];
  const float* W2 = (const float*)d_in[6];
  const float* b2 = (const float*)d_in[7];
  const float* W3 = (const float*)d_in[8];
  const float* b3 = (const float*)d_in[9];
  const float* W4 = (const float*)d_in[10];
  const float* b4 = (const float*)d_in[11];
  char* ws = (char*)d_ws;
  float* out = (float*)d_out;
  (void)in_sizes; (void)n_in; (void)ws_size; (void)out_size;

  // dest-granule threads: 32768+262144+262144+32768+262144+4096 = 856064
  prep_kernel<<<3344, 256, 0, stream>>>(t, x, om, W1, b1, W2, W3, W4, ws);
  fused_kernel<<<512, 256, 0, stream>>>(ws, b2, b3, b4, ew, out);
}

// Round 10
// 443.686 us; speedup vs baseline: 1.3643x; 1.0145x over previous
//
#include <hip/hip_runtime.h>
#include <hip/hip_bf16.h>

// ExpertODEEnsemble: E=8, D=64, H=512, B=32768.
// R10 = R9 (4-wave blocks, 64-row tiles, M=128xN=64 wave tile, 2 blocks/CU,
// e-loop + register combine, no atomics) +
//   (1) depth-2 A prefetch (2-kc lead >= L2/L3 latency; 8 waves/CU can't
//       cover it with TLP alone),
//   (2) same-expert ordering across all blocks (shared L2 sets / L1 hits),
//   (3) depth-2 A in the L4 loop.

typedef unsigned short ushort_t;
typedef unsigned int u32;
typedef unsigned long long u64;
typedef __attribute__((ext_vector_type(8))) short short8;
typedef __attribute__((ext_vector_type(4))) float floatx4;
typedef __attribute__((ext_vector_type(16))) float floatx16;
typedef __attribute__((ext_vector_type(4))) int intx4;

// ws layout (bytes); granule = 16 B = 8 bf16 along k
#define W1A_OFF 0u          // per e: byte w*16384 + kc*4096 + ol*1024 + lane*16
#define W2A_OFF 524288u     // per e: byte w*131072 + kc*4096 + ol*1024 + lane*16
#define W3A_OFF 4718592u
#define W4A_OFF 8912896u    // per e: byte o4*32768 + kc*1024 + lane*16
#define XB_OFF  9437184u    // x row-major bf16 [32768][64]
#define B1E_OFF 13631488u   // b1_eff fp32 [8][512]

static __device__ __forceinline__ u32 pk2bf(float a, float b) {
  union { __hip_bfloat162 h; u32 u; } v;
  v.h = __float22bfloat162_rn(make_float2(a, b));
  return v.u;
}

static __device__ __forceinline__ float pade_tanh(float x) {
  // tanh x = x(945+105x^2+x^4)/(945+420x^2+15x^4); |err|<=1e-4 for |x|<=2
  float x2 = x * x;
  float num = __builtin_fmaf(x2, __builtin_fmaf(x2, 1.0f, 105.0f), 945.0f);
  float den = __builtin_fmaf(x2, __builtin_fmaf(x2, 15.0f, 420.0f), 945.0f);
  return x * num * __builtin_amdgcn_rcpf(den);
}

static __device__ __forceinline__ void ald16(const void* g, void* l) {
  __builtin_amdgcn_global_load_lds((__attribute__((address_space(1))) void*)g,
                                   (__attribute__((address_space(3))) void*)l,
                                   16, 0, 0);
}

static __device__ __forceinline__ floatx16 mfma32(short8 a, short8 b, floatx16 c) {
  return __builtin_amdgcn_mfma_f32_32x32x16_bf16(a, b, c, 0, 0, 0);
}

// ---------------- prep: one 16B dest granule per thread ----------------------
__global__ __launch_bounds__(256) void prep_kernel(
    const float* __restrict__ t, const float* __restrict__ x,
    const float* __restrict__ omega, const float* __restrict__ W1,
    const float* __restrict__ b1, const float* __restrict__ W2,
    const float* __restrict__ W3, const float* __restrict__ W4,
    char* __restrict__ ws) {
  int i = blockIdx.x * 256 + threadIdx.x;
  if (i < 32768) {                       // W1A: e,outr<512,kg<8 (row stride 67)
    int e = i >> 12, rem = i & 4095, outr = rem >> 3, kg = rem & 7;
    int lane = (outr & 31) | ((kg & 1) << 5);
    int w = outr >> 7, ol = (outr >> 5) & 3, kc = kg >> 1;
    int dest = e * 4096 + ((w * 4 + kc) * 4 + ol) * 64 + lane;
    const float* s = W1 + (e * 512 + outr) * 67 + kg * 8;
    ((intx4*)(ws + W1A_OFF))[dest] = (intx4){
        (int)pk2bf(s[0], s[1]), (int)pk2bf(s[2], s[3]),
        (int)pk2bf(s[4], s[5]), (int)pk2bf(s[6], s[7])};
    return;
  }
  i -= 32768;
  if (i < 262144) {                      // W2A: e,outr<512,kg<64
    int e = i >> 15, rem = i & 32767, outr = rem >> 6, kg = rem & 63;
    int lane = (outr & 31) | ((kg & 1) << 5);
    int w = outr >> 7, ol = (outr >> 5) & 3, kc = kg >> 1;
    int dest = e * 32768 + ((w * 32 + kc) * 4 + ol) * 64 + lane;
    const floatx4* s = (const floatx4*)(W2 + ((e << 9) + outr) * 512 + (kg << 3));
    floatx4 lo = s[0], hi = s[1];
    ((intx4*)(ws + W2A_OFF))[dest] = (intx4){
        (int)pk2bf(lo[0], lo[1]), (int)pk2bf(lo[2], lo[3]),
        (int)pk2bf(hi[0], hi[1]), (int)pk2bf(hi[2], hi[3])};
    return;
  }
  i -= 262144;
  if (i < 262144) {                      // W3A
    int e = i >> 15, rem = i & 32767, outr = rem >> 6, kg = rem & 63;
    int lane = (outr & 31) | ((kg & 1) << 5);
    int w = outr >> 7, ol = (outr >> 5) & 3, kc = kg >> 1;
    int dest = e * 32768 + ((w * 32 + kc) * 4 + ol) * 64 + lane;
    const floatx4* s = (const floatx4*)(W3 + ((e << 9) + outr) * 512 + (kg << 3));
    floatx4 lo = s[0], hi = s[1];
    ((intx4*)(ws + W3A_OFF))[dest] = (intx4){
        (int)pk2bf(lo[0], lo[1]), (int)pk2bf(lo[2], lo[3]),
        (int)pk2bf(hi[0], hi[1]), (int)pk2bf(hi[2], hi[3])};
    return;
  }
  i -= 262144;
  if (i < 32768) {                       // W4A: e,outr<64,kg<64
    int e = i >> 12, rem = i & 4095, outr = rem >> 6, kg = rem & 63;
    int lane = (outr & 31) | ((kg & 1) << 5);
    int o4 = outr >> 5, kc = kg >> 1;
    int dest = e * 4096 + (o4 * 32 + kc) * 64 + lane;
    const floatx4* s = (const floatx4*)(W4 + ((e << 6) + outr) * 512 + (kg << 3));
    floatx4 lo = s[0], hi = s[1];
    ((intx4*)(ws + W4A_OFF))[dest] = (intx4){
        (int)pk2bf(lo[0], lo[1]), (int)pk2bf(lo[2], lo[3]),
        (int)pk2bf(hi[0], hi[1]), (int)pk2bf(hi[2], hi[3])};
    return;
  }
  i -= 32768;
  if (i < 262144) {                      // x -> bf16, row-major
    const floatx4* s = (const floatx4*)(x + i * 8);
    floatx4 lo = s[0], hi = s[1];
    ((intx4*)(ws + XB_OFF))[i] = (intx4){
        (int)pk2bf(lo[0], lo[1]), (int)pk2bf(lo[2], lo[3]),
        (int)pk2bf(hi[0], hi[1]), (int)pk2bf(hi[2], hi[3])};
    return;
  }
  i -= 262144;
  if (i < 4096) {                        // b1_eff: fold t/sin/cos cols of W1
    float tv = t[0];
    int e = i >> 9;
    float om = omega[e];
    ((float*)(ws + B1E_OFF))[i] = b1[i] + tv * W1[i * 67 + 64]
        + sinf(om * tv) * W1[i * 67 + 65] + cosf(om * tv) * W1[i * 67 + 66];
  }
}

// act LDS (64 rows): granule f(row, koct) = (koct>>1)*132 + (row>>5)*64
//                    + (koct&1)*32 + (row&31);  kc-slab stride 2112 B.
// B-read (kc, nt): byte kc*2112 + nt*1024 + lane*16 -> stride-1, conflict-free.

template <int NKC, bool WRAP>
static __device__ __forceinline__ void mlp_layer(
    const char* __restrict__ bsrc, char* __restrict__ dst,
    int lane, int w, int q1, int r31,
    const char* __restrict__ Abase, const float* __restrict__ bias) {
  const int voff = lane * 16;
  const char* sp = Abase + w * (NKC * 4096) + voff;
  const char* bp = bsrc + voff;

  floatx16 acc[4][2];
#pragma unroll
  for (int ol = 0; ol < 4; ++ol) {
    int fe0 = (4 * w + ol) * 32 + 4 * q1;
#pragma unroll
    for (int g = 0; g < 4; ++g) {
      floatx4 bv = *(const floatx4*)(bias + fe0 + 8 * g);
#pragma unroll
      for (int nt = 0; nt < 2; ++nt) {
        acc[ol][nt][4 * g + 0] = bv[0];
        acc[ol][nt][4 * g + 1] = bv[1];
        acc[ol][nt][4 * g + 2] = bv[2];
        acc[ol][nt][4 * g + 3] = bv[3];
      }
    }
  }
  // A: depth-2 pipeline (2-kc lead covers L2/L3 latency). B: depth-1 (LDS).
  short8 aA0 = *(const short8*)(sp);
  short8 aA1 = *(const short8*)(sp + 1024);
  short8 aA2 = *(const short8*)(sp + 2048);
  short8 aA3 = *(const short8*)(sp + 3072);
  short8 aB0 = *(const short8*)(sp + 4096);
  short8 aB1 = *(const short8*)(sp + 5120);
  short8 aB2 = *(const short8*)(sp + 6144);
  short8 aB3 = *(const short8*)(sp + 7168);
  sp += 8192;
  short8 b0 = *(const short8*)(bp);
  short8 b1 = *(const short8*)(bp + 1024);

#pragma unroll 4
  for (int kc = 0; kc < NKC; ++kc) {
    // prefetch A of kc+2 (overrun lands in ws, never consumed)
    short8 aN0 = *(const short8*)(sp);
    short8 aN1 = *(const short8*)(sp + 1024);
    short8 aN2 = *(const short8*)(sp + 2048);
    short8 aN3 = *(const short8*)(sp + 3072);
    sp += 4096;
    // prefetch B of kc+1 (wrap for L1; overrun into x region otherwise)
    const char* bn = WRAP ? (bsrc + voff + (((kc + 1) & (NKC - 1)) * 2112))
                          : (bsrc + voff + (kc + 1) * 2112);
    short8 bN0 = *(const short8*)(bn);
    short8 bN1 = *(const short8*)(bn + 1024);
    acc[0][0] = mfma32(aA0, b0, acc[0][0]);
    acc[1][0] = mfma32(aA1, b0, acc[1][0]);
    acc[2][0] = mfma32(aA2, b0, acc[2][0]);
    acc[3][0] = mfma32(aA3, b0, acc[3][0]);
    acc[0][1] = mfma32(aA0, b1, acc[0][1]);
    acc[1][1] = mfma32(aA1, b1, acc[1][1]);
    acc[2][1] = mfma32(aA2, b1, acc[2][1]);
    acc[3][1] = mfma32(aA3, b1, acc[3][1]);
    aA0 = aB0; aA1 = aB1; aA2 = aB2; aA3 = aB3;
    aB0 = aN0; aB1 = aN1; aB2 = aN2; aB3 = aN3;
    b0 = bN0; b1 = bN1;
  }
  __syncthreads();                               // all act reads done
#pragma unroll
  for (int ol = 0; ol < 4; ++ol) {
    int o_abs = 4 * w + ol;
#pragma unroll
    for (int g = 0; g < 4; ++g) {
      int koct = o_abs * 4 + g;
      char* base = dst + ((((koct >> 1) * 132 + (koct & 1) * 32 + r31) << 4) + q1 * 8);
#pragma unroll
      for (int nt = 0; nt < 2; ++nt) {
        float v0 = pade_tanh(acc[ol][nt][4 * g + 0]);
        float v1 = pade_tanh(acc[ol][nt][4 * g + 1]);
        float v2 = pade_tanh(acc[ol][nt][4 * g + 2]);
        float v3 = pade_tanh(acc[ol][nt][4 * g + 3]);
        u32 lo = pk2bf(v0, v1), hi = pk2bf(v2, v3);
        *(u64*)(base + nt * 1024) = ((u64)hi << 32) | lo;
      }
    }
  }
  __syncthreads();                               // act_{n+1} visible
}

__global__ __launch_bounds__(256, 2) void fused_kernel(
    const char* __restrict__ ws, const float* __restrict__ b2,
    const float* __restrict__ b3, const float* __restrict__ b4,
    const float* __restrict__ ew, float* __restrict__ out) {
  __shared__ char smem[76032];           // 67584 act | 8448 x region
  char* xreg = smem + 67584;
  const int t = threadIdx.x, lane = t & 63, w = t >> 6;   // 4 waves
  const int q1 = lane >> 5, r31 = lane & 31;
  const int row0 = blockIdx.x << 6;      // 64-row tile, 512 blocks (2/CU)
  const int voff = lane * 16;

  // stage x once: wave w -> kc slab w, halves h=0,1
  const ushort_t* xb = (const ushort_t*)(ws + XB_OFF);
  ald16(xb + (row0 + r31) * 64 + w * 16 + q1 * 8, xreg + (w * 132) * 16);
  ald16(xb + (row0 + 32 + r31) * 64 + w * 16 + q1 * 8, xreg + (w * 132 + 64) * 16);

  // L4 assignment: o4 = w&1 (feat half), nt4 = w>>1 (row half), full K
  const int o4 = w & 1, nt4 = w >> 1;
  const int row_l4 = row0 + nt4 * 32 + r31;
  const int fe0 = o4 * 32 + 4 * q1;
  floatx16 out_acc = {};

  __syncthreads();                       // x staged

  // same-expert ordering: all blocks stream expert ei together -> shared L2
  // sets per XCD, incidental L1 hits between co-resident blocks.
  for (int e = 0; e < 8; ++e) {
    const float sc = ew[row_l4 * 8 + e];

    mlp_layer<4, true>(xreg, smem, lane, w, q1, r31,
                       ws + W1A_OFF + e * 65536,
                       (const float*)(ws + B1E_OFF) + e * 512);
    mlp_layer<32, false>(smem, smem, lane, w, q1, r31,
                         ws + W2A_OFF + e * 524288, b2 + e * 512);
    mlp_layer<32, false>(smem, smem, lane, w, q1, r31,
                         ws + W3A_OFF + e * 524288, b3 + e * 512);

    // L4: full K=512 per wave, depth-2 A, depth-1 B
    {
      const char* sp = ws + W4A_OFF + e * 65536 + o4 * 32768 + voff;
      const char* bp = smem + nt4 * 1024 + voff;
      floatx16 acc = {};
      short8 a0 = *(const short8*)(sp);
      short8 a1 = *(const short8*)(sp + 1024);
      sp += 2048;
      short8 b = *(const short8*)(bp);
#pragma unroll 4
      for (int kc = 0; kc < 32; ++kc) {
        short8 an = *(const short8*)(sp);        // kc+2; overrun: in-ws
        sp += 1024;
        short8 bn = *(const short8*)(bp + 2112); // kc+1; overrun: xreg, unused
        acc = mfma32(a0, b, acc);
        a0 = a1; a1 = an; b = bn;
        bp += 2112;
      }
      const float* bpb = b4 + e * 64 + fe0;
#pragma unroll
      for (int g = 0; g < 4; ++g) {
        floatx4 bv = *(const floatx4*)(bpb + 8 * g);
        out_acc[4 * g + 0] += sc * (acc[4 * g + 0] + bv[0]);
        out_acc[4 * g + 1] += sc * (acc[4 * g + 1] + bv[1]);
        out_acc[4 * g + 2] += sc * (acc[4 * g + 2] + bv[2]);
        out_acc[4 * g + 3] += sc * (acc[4 * g + 3] + bv[3]);
      }
    }
    // next expert's L1 reads only xreg; its post-kc-loop barrier orders these
    // L4 act reads before the L1 epilogue overwrites the act region.
  }

  // direct store (full-K waves: no partner merge)
  float* orow = out + row_l4 * 64 + fe0;
#pragma unroll
  for (int g = 0; g < 4; ++g) {
    floatx4 v = {out_acc[4 * g + 0], out_acc[4 * g + 1],
                 out_acc[4 * g + 2], out_acc[4 * g + 3]};
    *(floatx4*)(orow + 8 * g) = v;
  }
}

extern "C" void kernel_launch(void* const* d_in, const int* in_sizes, int n_in,
                              void* d_out, int out_size, void* d_ws, size_t ws_size,
                              hipStream_t stream) {
  const float* t  = (const float*)d_in[0];
  const float* x  = (const float*)d_in[1];
  const float* ew = (const float*)d_in[2];
  const float* om = (const float*)d_in[3];
  const float* W1 = (const float*)d_in[4];
  const float* b1 = (const float*)d_in[5];
  const float* W2 = (const float*)d_in[6];
  const float* b2 = (const float*)d_in[7];
  const float* W3 = (const float*)d_in[8];
  const float* b3 = (const float*)d_in[9];
  const float* W4 = (const float*)d_in[10];
  const float* b4 = (const float*)d_in[11];
  char* ws = (char*)d_ws;
  float* out = (float*)d_out;
  (void)in_sizes; (void)n_in; (void)ws_size; (void)out_size;

  // dest-granule threads: 32768+262144+262144+32768+262144+4096 = 856064
  prep_kernel<<<3344, 256, 0, stream>>>(t, x, om, W1, b1, W2, W3, W4, ws);
  fused_kernel<<<512, 256, 0, stream>>>(ws, b2, b3, b4, ew, out);
}